// Round 4
// baseline (113.840 us; speedup 1.0000x reference)
//
#include <hip/hip_runtime.h>

// EquivariantLinear = per-head circular correlation on Z_8^3, via 8x8x8 FFT:
//   out = IDFT( DFT(x) * V ),  V[h][f] = conj(DFT(W_h))[f] / 512.
// Round-4 change: pair-pack 2 channels per thread so all LDS traffic is
// b64/b128 (was 160 scalar b32/thread -> LDS-issue-bound ~25us). Layout
// [pair][p1][p2][p3][2ch], strides chosen for 16B alignment + bank spread.

#define S2C 0.70710678118654752f
#define ST2 20     // p2 stride (words): 16 + 4 pad (keeps b128 align, spreads banks)
#define ST1 164    // p1 stride: 8*20 + 4 pad  (164 mod 32 = 4)
#define STP 1312   // pair stride: 8*164

// ---------------------------------------------------------------- DFT-8 in-place
template <bool INV>
__device__ __forceinline__ void dft8(float* R, float* I)
{
    float t0r = R[0] + R[4], t0i = I[0] + I[4];
    float t1r = R[1] + R[5], t1i = I[1] + I[5];
    float t2r = R[2] + R[6], t2i = I[2] + I[6];
    float t3r = R[3] + R[7], t3i = I[3] + I[7];
    float b0r = R[0] - R[4], b0i = I[0] - I[4];
    float d1r = R[1] - R[5], d1i = I[1] - I[5];
    float d2r = R[2] - R[6], d2i = I[2] - I[6];
    float d3r = R[3] - R[7], d3i = I[3] - I[7];
    float b1r, b1i, b2r, b2i, b3r, b3i;
    if (!INV) {
        b1r = (d1r + d1i) * S2C;  b1i = (d1i - d1r) * S2C;
        b2r = d2i;                b2i = -d2r;
        b3r = (d3i - d3r) * S2C;  b3i = -(d3r + d3i) * S2C;
    } else {
        b1r = (d1r - d1i) * S2C;  b1i = (d1i + d1r) * S2C;
        b2r = -d2i;               b2i = d2r;
        b3r = -(d3r + d3i) * S2C; b3i = (d3r - d3i) * S2C;
    }
    float u0r = t0r + t2r, u0i = t0i + t2i;
    float u1r = t1r + t3r, u1i = t1i + t3i;
    float u2r = t0r - t2r, u2i = t0i - t2i;
    float e3r = t1r - t3r, e3i = t1i - t3i;
    float u3r, u3i;
    if (!INV) { u3r = e3i;  u3i = -e3r; }
    else      { u3r = -e3i; u3i = e3r;  }
    R[0] = u0r + u1r; I[0] = u0i + u1i;
    R[4] = u0r - u1r; I[4] = u0i - u1i;
    R[2] = u2r + u3r; I[2] = u2i + u3i;
    R[6] = u2r - u3r; I[6] = u2i - u3i;
    float v0r = b0r + b2r, v0i = b0i + b2i;
    float v1r = b1r + b3r, v1i = b1i + b3i;
    float v2r = b0r - b2r, v2i = b0i - b2i;
    float w3r = b1r - b3r, w3i = b1i - b3i;
    float v3r, v3i;
    if (!INV) { v3r = w3i;  v3i = -w3r; }
    else      { v3r = -w3i; v3i = w3r;  }
    R[1] = v0r + v1r; I[1] = v0i + v1i;
    R[5] = v0r - v1r; I[5] = v0i - v1i;
    R[3] = v2r + v3r; I[3] = v2i + v3i;
    R[7] = v2r - v3r; I[7] = v2i - v3i;
}

// ---------------------------------------------------------------- prep kernel
__device__ const float CTAB8[8] = {1.f, S2C, 0.f, -S2C, -1.f, -S2C, 0.f, S2C};
__device__ const float STAB8[8] = {0.f, S2C, 1.f, S2C, 0.f, -S2C, -1.f, -S2C};

__global__ __launch_bounds__(256)
void eqfft_prep(const float* __restrict__ basis,
                const float* __restrict__ kparam,
                float2* __restrict__ V)
{
    __shared__ float Wl[512];
    __shared__ float CT[8], ST[8];
    const int tid = threadIdx.x;
    const int blk = blockIdx.x;    // 128 blocks: h = blk>>4, f-base = (blk&15)*32
    const int h   = blk >> 4;
    if (tid < 8) { CT[tid] = CTAB8[tid]; ST[tid] = STAB8[tid]; }
    #pragma unroll
    for (int t = 0; t < 2; ++t) {
        const int g = tid * 2 + t;
        const float* bp = basis + g * 24;
        float acc = 0.f;
        #pragma unroll
        for (int s = 0; s < 24; ++s) acc += bp[s] * kparam[s * 8 + h];
        Wl[(g & 63) * 8 + (g >> 6)] = acc;
    }
    __syncthreads();
    const int f  = (blk & 15) * 32 + (tid >> 3);
    const int g1 = tid & 7;
    const int f1 = f >> 6, f2 = (f >> 3) & 7, f3 = f & 7;
    const int kb = (f1 * g1) & 7;
    float pr = 0.f, pi = 0.f;
    for (int g2 = 0; g2 < 8; ++g2) {
        const int k2 = kb + f2 * g2;
        const float* wrow = &Wl[g2 * 64 + g1];
        #pragma unroll
        for (int g3 = 0; g3 < 8; ++g3) {
            const int k = (k2 + f3 * g3) & 7;
            const float w = wrow[g3 * 8];
            pr += w * CT[k];
            pi += w * ST[k];
        }
    }
    pr += __shfl_xor(pr, 1); pi += __shfl_xor(pi, 1);
    pr += __shfl_xor(pr, 2); pi += __shfl_xor(pi, 2);
    pr += __shfl_xor(pr, 4); pi += __shfl_xor(pi, 4);
    if (g1 == 0)
        V[h * 512 + f] = make_float2(pr * (1.f / 512.f), pi * (1.f / 512.f));
}

// ---------------------------------------------------------------- main kernel
// 2048 WGs x 256 thr. WG = (b, 8-ch tile) = 4 channel-pairs.
// Thread = (pair = tid>>6, line = tid&63); each pass moves both pair members.
__global__ __launch_bounds__(256, 3)
void eqfft_main(const float* __restrict__ x,
                const float2* __restrict__ V,
                float* __restrict__ out)
{
    __shared__ __align__(16) float reA[4 * STP];   // 21 KB
    __shared__ __align__(16) float imA[4 * STP];   // 21 KB

    const int tid = threadIdx.x;
    const int bid = blockIdx.x;
    const int b   = bid >> 6;
    const int ch0 = (bid & 63) * 8;

    const float* xb = x   + (size_t)b * 262144 + ch0;
    float*       ob = out + (size_t)b * 262144 + ch0;

    // stage-in: 8 ch x 512 p = 1024 float4; each -> 2 b64 LDS writes
    #pragma unroll
    for (int i = 0; i < 4; ++i) {
        const int v  = i * 256 + tid;
        const int pt = v >> 1;
        const int c4 = (v & 1) * 4;
        const float4 d = *(const float4*)(xb + pt * 512 + c4);
        const int base = (pt >> 6) * ST1 + ((pt >> 3) & 7) * ST2 + (pt & 7) * 2;
        const int pr = c4 >> 1;              // pair 0 or 2
        *(float2*)(reA + pr * STP + base)       = make_float2(d.x, d.y);
        *(float2*)(reA + (pr + 1) * STP + base) = make_float2(d.z, d.w);
    }
    __syncthreads();

    const int pair = tid >> 6;
    const int line = tid & 63;
    float R0[8], I0[8], R1[8], I1[8];

    // pass 3 fwd (along p3, contiguous: 4x b128 read, real input)
    {
        float* rp = reA + pair * STP + (line >> 3) * ST1 + (line & 7) * ST2;
        float* ip = imA + pair * STP + (line >> 3) * ST1 + (line & 7) * ST2;
        #pragma unroll
        for (int k = 0; k < 4; ++k) {
            const float4 d = *(const float4*)(rp + 4 * k);
            R0[2*k] = d.x; R1[2*k] = d.y; R0[2*k+1] = d.z; R1[2*k+1] = d.w;
            I0[2*k] = 0.f; I1[2*k] = 0.f; I0[2*k+1] = 0.f; I1[2*k+1] = 0.f;
        }
        dft8<false>(R0, I0); dft8<false>(R1, I1);
        #pragma unroll
        for (int k = 0; k < 4; ++k) {
            *(float4*)(rp + 4*k) = make_float4(R0[2*k], R1[2*k], R0[2*k+1], R1[2*k+1]);
            *(float4*)(ip + 4*k) = make_float4(I0[2*k], I1[2*k], I0[2*k+1], I1[2*k+1]);
        }
    }
    __syncthreads();

    // pass 2 fwd (along p2, stride ST2, b64 per element)
    {
        float* rp = reA + pair * STP + (line >> 3) * ST1 + (line & 7) * 2;
        float* ip = imA + pair * STP + (line >> 3) * ST1 + (line & 7) * 2;
        #pragma unroll
        for (int j = 0; j < 8; ++j) {
            const float2 a = *(const float2*)(rp + j * ST2);
            const float2 c = *(const float2*)(ip + j * ST2);
            R0[j] = a.x; R1[j] = a.y; I0[j] = c.x; I1[j] = c.y;
        }
        dft8<false>(R0, I0); dft8<false>(R1, I1);
        #pragma unroll
        for (int j = 0; j < 8; ++j) {
            *(float2*)(rp + j * ST2) = make_float2(R0[j], R1[j]);
            *(float2*)(ip + j * ST2) = make_float2(I0[j], I1[j]);
        }
    }
    __syncthreads();

    // pass 1 fwd + pointwise V + pass 1 inv (along p1, stride ST1) — fused
    {
        const int p2 = line >> 3, p3 = line & 7;
        // V loads first (hide L2 latency under LDS reads + fwd dft)
        const float2* v0 = V + (pair * 2 + 0) * 512 + p2 * 8 + p3;
        const float2* v1 = V + (pair * 2 + 1) * 512 + p2 * 8 + p3;
        float2 va[8], vb[8];
        #pragma unroll
        for (int j = 0; j < 8; ++j) { va[j] = v0[j << 6]; vb[j] = v1[j << 6]; }

        float* rp = reA + pair * STP + p2 * ST2 + p3 * 2;
        float* ip = imA + pair * STP + p2 * ST2 + p3 * 2;
        #pragma unroll
        for (int j = 0; j < 8; ++j) {
            const float2 a = *(const float2*)(rp + j * ST1);
            const float2 c = *(const float2*)(ip + j * ST1);
            R0[j] = a.x; R1[j] = a.y; I0[j] = c.x; I1[j] = c.y;
        }
        dft8<false>(R0, I0); dft8<false>(R1, I1);
        #pragma unroll
        for (int j = 0; j < 8; ++j) {
            float nr = R0[j] * va[j].x - I0[j] * va[j].y;
            I0[j]    = R0[j] * va[j].y + I0[j] * va[j].x;
            R0[j]    = nr;
            nr       = R1[j] * vb[j].x - I1[j] * vb[j].y;
            I1[j]    = R1[j] * vb[j].y + I1[j] * vb[j].x;
            R1[j]    = nr;
        }
        dft8<true>(R0, I0); dft8<true>(R1, I1);
        #pragma unroll
        for (int j = 0; j < 8; ++j) {
            *(float2*)(rp + j * ST1) = make_float2(R0[j], R1[j]);
            *(float2*)(ip + j * ST1) = make_float2(I0[j], I1[j]);
        }
    }
    __syncthreads();

    // pass 2 inv
    {
        float* rp = reA + pair * STP + (line >> 3) * ST1 + (line & 7) * 2;
        float* ip = imA + pair * STP + (line >> 3) * ST1 + (line & 7) * 2;
        #pragma unroll
        for (int j = 0; j < 8; ++j) {
            const float2 a = *(const float2*)(rp + j * ST2);
            const float2 c = *(const float2*)(ip + j * ST2);
            R0[j] = a.x; R1[j] = a.y; I0[j] = c.x; I1[j] = c.y;
        }
        dft8<true>(R0, I0); dft8<true>(R1, I1);
        #pragma unroll
        for (int j = 0; j < 8; ++j) {
            *(float2*)(rp + j * ST2) = make_float2(R0[j], R1[j]);
            *(float2*)(ip + j * ST2) = make_float2(I0[j], I1[j]);
        }
    }
    __syncthreads();

    // pass 3 inv (result real; write re only, b128)
    {
        float* rp = reA + pair * STP + (line >> 3) * ST1 + (line & 7) * ST2;
        float* ip = imA + pair * STP + (line >> 3) * ST1 + (line & 7) * ST2;
        #pragma unroll
        for (int k = 0; k < 4; ++k) {
            const float4 a = *(const float4*)(rp + 4 * k);
            const float4 c = *(const float4*)(ip + 4 * k);
            R0[2*k] = a.x; R1[2*k] = a.y; R0[2*k+1] = a.z; R1[2*k+1] = a.w;
            I0[2*k] = c.x; I1[2*k] = c.y; I0[2*k+1] = c.z; I1[2*k+1] = c.w;
        }
        dft8<true>(R0, I0); dft8<true>(R1, I1);
        #pragma unroll
        for (int k = 0; k < 4; ++k)
            *(float4*)(rp + 4*k) = make_float4(R0[2*k], R1[2*k], R0[2*k+1], R1[2*k+1]);
    }
    __syncthreads();

    // copy-out: float4 = 2 b64 LDS reads
    #pragma unroll
    for (int i = 0; i < 4; ++i) {
        const int v  = i * 256 + tid;
        const int pt = v >> 1;
        const int c4 = (v & 1) * 4;
        const int base = (pt >> 6) * ST1 + ((pt >> 3) & 7) * ST2 + (pt & 7) * 2;
        const int pr = c4 >> 1;
        const float2 a = *(const float2*)(reA + pr * STP + base);
        const float2 c = *(const float2*)(reA + (pr + 1) * STP + base);
        *(float4*)(ob + pt * 512 + c4) = make_float4(a.x, a.y, c.x, c.y);
    }
}

extern "C" void kernel_launch(void* const* d_in, const int* in_sizes, int n_in,
                              void* d_out, int out_size, void* d_ws, size_t ws_size,
                              hipStream_t stream)
{
    const float* x      = (const float*)d_in[0];   // [32][512][512]
    const float* basis  = (const float*)d_in[1];   // [512][24]
    const float* kparam = (const float*)d_in[2];   // [24][8]
    float* out          = (float*)d_out;
    float2* V           = (float2*)d_ws;           // 8*512*8B = 32 KB scratch

    hipLaunchKernelGGL(eqfft_prep, dim3(128),  dim3(256), 0, stream, basis, kparam, V);
    hipLaunchKernelGGL(eqfft_main, dim3(2048), dim3(256), 0, stream, x, V, out);
}

// Round 5
// 99.739 us; speedup vs baseline: 1.1414x; 1.1414x over previous
//
#include <hip/hip_runtime.h>

// EquivariantLinear = per-head circular correlation on Z_8^3 via 8x8x8 FFT:
//   out = IDFT( DFT(x) * V ),  V[h][f] = conj(DFT(W_h))[f] / 512.
// Round-5: complex-pack channel pairs (c, c+8) — same head => same V, and
// linearity + real outputs mean re/im of the packed result ARE the two
// channels (no Hermitian unpack). Halves LDS bytes/instrs and VALU.
// WG = (b, 16ch) = 8 packed cubes, 36.6KB LDS -> 4 blocks/CU; 64B rows ->
// exact HBM fetch granularity (round-4 was 2x over-fetch at 32B rows).

#define S2C 0.70710678118654752f
#define S2  18     // p2 stride (floats): 8 complex + 1 complex pad
#define S1  146    // p1 stride: 8*18 + 2
#define CST 1172   // cube stride: 8*146 + 4  (1172%32=20 spreads cubes)

// ---------------------------------------------------------------- DFT-8 in-place
template <bool INV>
__device__ __forceinline__ void dft8(float* R, float* I)
{
    float t0r = R[0] + R[4], t0i = I[0] + I[4];
    float t1r = R[1] + R[5], t1i = I[1] + I[5];
    float t2r = R[2] + R[6], t2i = I[2] + I[6];
    float t3r = R[3] + R[7], t3i = I[3] + I[7];
    float b0r = R[0] - R[4], b0i = I[0] - I[4];
    float d1r = R[1] - R[5], d1i = I[1] - I[5];
    float d2r = R[2] - R[6], d2i = I[2] - I[6];
    float d3r = R[3] - R[7], d3i = I[3] - I[7];
    float b1r, b1i, b2r, b2i, b3r, b3i;
    if (!INV) {
        b1r = (d1r + d1i) * S2C;  b1i = (d1i - d1r) * S2C;
        b2r = d2i;                b2i = -d2r;
        b3r = (d3i - d3r) * S2C;  b3i = -(d3r + d3i) * S2C;
    } else {
        b1r = (d1r - d1i) * S2C;  b1i = (d1i + d1r) * S2C;
        b2r = -d2i;               b2i = d2r;
        b3r = -(d3r + d3i) * S2C; b3i = (d3r - d3i) * S2C;
    }
    float u0r = t0r + t2r, u0i = t0i + t2i;
    float u1r = t1r + t3r, u1i = t1i + t3i;
    float u2r = t0r - t2r, u2i = t0i - t2i;
    float e3r = t1r - t3r, e3i = t1i - t3i;
    float u3r, u3i;
    if (!INV) { u3r = e3i;  u3i = -e3r; }
    else      { u3r = -e3i; u3i = e3r;  }
    R[0] = u0r + u1r; I[0] = u0i + u1i;
    R[4] = u0r - u1r; I[4] = u0i - u1i;
    R[2] = u2r + u3r; I[2] = u2i + u3i;
    R[6] = u2r - u3r; I[6] = u2i - u3i;
    float v0r = b0r + b2r, v0i = b0i + b2i;
    float v1r = b1r + b3r, v1i = b1i + b3i;
    float v2r = b0r - b2r, v2i = b0i - b2i;
    float w3r = b1r - b3r, w3i = b1i - b3i;
    float v3r, v3i;
    if (!INV) { v3r = w3i;  v3i = -w3r; }
    else      { v3r = -w3i; v3i = w3r;  }
    R[1] = v0r + v1r; I[1] = v0i + v1i;
    R[5] = v0r - v1r; I[5] = v0i - v1i;
    R[3] = v2r + v3r; I[3] = v2i + v3i;
    R[7] = v2r - v3r; I[7] = v2i - v3i;
}

// ---------------------------------------------------------------- prep kernel
__device__ const float CTAB8[8] = {1.f, S2C, 0.f, -S2C, -1.f, -S2C, 0.f, S2C};
__device__ const float STAB8[8] = {0.f, S2C, 1.f, S2C, 0.f, -S2C, -1.f, -S2C};

__global__ __launch_bounds__(256)
void eqfft_prep(const float* __restrict__ basis,
                const float* __restrict__ kparam,
                float2* __restrict__ V)
{
    __shared__ float Wl[512];
    __shared__ float CT[8], ST[8];
    const int tid = threadIdx.x;
    const int blk = blockIdx.x;    // 128 blocks: h = blk>>4, f-base = (blk&15)*32
    const int h   = blk >> 4;
    if (tid < 8) { CT[tid] = CTAB8[tid]; ST[tid] = STAB8[tid]; }
    #pragma unroll
    for (int t = 0; t < 2; ++t) {
        const int g = tid * 2 + t;
        const float* bp = basis + g * 24;
        float acc = 0.f;
        #pragma unroll
        for (int s = 0; s < 24; ++s) acc += bp[s] * kparam[s * 8 + h];
        Wl[(g & 63) * 8 + (g >> 6)] = acc;
    }
    __syncthreads();
    const int f  = (blk & 15) * 32 + (tid >> 3);
    const int g1 = tid & 7;
    const int f1 = f >> 6, f2 = (f >> 3) & 7, f3 = f & 7;
    const int kb = (f1 * g1) & 7;
    float pr = 0.f, pi = 0.f;
    for (int g2 = 0; g2 < 8; ++g2) {
        const int k2 = kb + f2 * g2;
        const float* wrow = &Wl[g2 * 64 + g1];
        #pragma unroll
        for (int g3 = 0; g3 < 8; ++g3) {
            const int k = (k2 + f3 * g3) & 7;
            const float w = wrow[g3 * 8];
            pr += w * CT[k];
            pi += w * ST[k];
        }
    }
    pr += __shfl_xor(pr, 1); pi += __shfl_xor(pi, 1);
    pr += __shfl_xor(pr, 2); pi += __shfl_xor(pi, 2);
    pr += __shfl_xor(pr, 4); pi += __shfl_xor(pi, 4);
    if (g1 == 0)
        V[h * 512 + f] = make_float2(pr * (1.f / 512.f), pi * (1.f / 512.f));
}

// ---------------------------------------------------------------- main kernel
// 1024 WGs x 256 thr. WG = (b = bid>>5, ch-tile c0 = (bid&31)*16) = 8 packed
// cubes: cube q holds z = x[c0+q] + i*x[c0+q+8]  (head == q since c0%16==0).
// Thread = (q = tid>>5, e = tid&31); per pass handles pencils P = 2e, 2e+1.
__global__ __launch_bounds__(256, 4)
void eqfft_main(const float* __restrict__ x,
                const float2* __restrict__ V,
                float* __restrict__ out)
{
    __shared__ __align__(16) float lds[8 * CST];   // 36.6 KB

    const int tid = threadIdx.x;
    const int bid = blockIdx.x;
    const int b   = bid >> 5;
    const int c0  = (bid & 31) * 16;

    const float* xb = x   + (size_t)b * 262144 + c0;
    float*       ob = out + (size_t)b * 262144 + c0;

    // stage-in + pack: rows are 64B contiguous per WG (exact fetch granularity)
    #pragma unroll
    for (int t = 0; t < 4; ++t) {
        const int G = t * 256 + tid;
        const int p = G >> 1;
        const int u = G & 1;
        const float4 A  = *(const float4*)(xb + p * 512 + u * 4);
        const float4 Bv = *(const float4*)(xb + p * 512 + u * 4 + 8);
        const int base = (p >> 6) * S1 + ((p >> 3) & 7) * S2 + (p & 7) * 2;
        float* dst = lds + (u * 4) * CST + base;
        *(float2*)(dst + 0 * CST) = make_float2(A.x, Bv.x);
        *(float2*)(dst + 1 * CST) = make_float2(A.y, Bv.y);
        *(float2*)(dst + 2 * CST) = make_float2(A.z, Bv.z);
        *(float2*)(dst + 3 * CST) = make_float2(A.w, Bv.w);
    }
    __syncthreads();

    const int q = tid >> 5;
    const int e = tid & 31;
    float R0[8], I0[8], R1[8], I1[8];

    // pass 3 fwd: pencil (p1,p2), stride 2 floats (contiguous complex)
    {
        const int P0 = 2 * e, P1 = 2 * e + 1;
        float* pa = lds + q * CST + (P0 >> 3) * S1 + (P0 & 7) * S2;
        float* pb = lds + q * CST + (P1 >> 3) * S1 + (P1 & 7) * S2;
        #pragma unroll
        for (int j = 0; j < 8; ++j) {
            const float2 za = *(const float2*)(pa + 2 * j);
            const float2 zb = *(const float2*)(pb + 2 * j);
            R0[j] = za.x; I0[j] = za.y; R1[j] = zb.x; I1[j] = zb.y;
        }
        dft8<false>(R0, I0); dft8<false>(R1, I1);
        #pragma unroll
        for (int j = 0; j < 8; ++j) {
            *(float2*)(pa + 2 * j) = make_float2(R0[j], I0[j]);
            *(float2*)(pb + 2 * j) = make_float2(R1[j], I1[j]);
        }
    }
    __syncthreads();

    // pass 2 fwd: pencil (p1,p3), stride S2
    {
        const int P0 = 2 * e, P1 = 2 * e + 1;
        float* pa = lds + q * CST + (P0 >> 3) * S1 + (P0 & 7) * 2;
        float* pb = lds + q * CST + (P1 >> 3) * S1 + (P1 & 7) * 2;
        #pragma unroll
        for (int j = 0; j < 8; ++j) {
            const float2 za = *(const float2*)(pa + S2 * j);
            const float2 zb = *(const float2*)(pb + S2 * j);
            R0[j] = za.x; I0[j] = za.y; R1[j] = zb.x; I1[j] = zb.y;
        }
        dft8<false>(R0, I0); dft8<false>(R1, I1);
        #pragma unroll
        for (int j = 0; j < 8; ++j) {
            *(float2*)(pa + S2 * j) = make_float2(R0[j], I0[j]);
            *(float2*)(pb + S2 * j) = make_float2(R1[j], I1[j]);
        }
    }
    __syncthreads();

    // pass 1 fwd + pointwise V + pass 1 inv: pencil (p2,p3), stride S1 — fused
    {
        const int P0 = 2 * e, P1 = 2 * e + 1;
        const int p2a = P0 >> 3, p3a = P0 & 7;
        const int p2b = P1 >> 3, p3b = P1 & 7;
        const float2* v0 = V + q * 512 + p2a * 8 + p3a;
        const float2* v1 = V + q * 512 + p2b * 8 + p3b;
        float2 va[8], vb[8];
        #pragma unroll
        for (int j = 0; j < 8; ++j) { va[j] = v0[j << 6]; vb[j] = v1[j << 6]; }

        float* pa = lds + q * CST + p2a * S2 + p3a * 2;
        float* pb = lds + q * CST + p2b * S2 + p3b * 2;
        #pragma unroll
        for (int j = 0; j < 8; ++j) {
            const float2 za = *(const float2*)(pa + S1 * j);
            const float2 zb = *(const float2*)(pb + S1 * j);
            R0[j] = za.x; I0[j] = za.y; R1[j] = zb.x; I1[j] = zb.y;
        }
        dft8<false>(R0, I0); dft8<false>(R1, I1);
        #pragma unroll
        for (int j = 0; j < 8; ++j) {
            float nr = R0[j] * va[j].x - I0[j] * va[j].y;
            I0[j]    = R0[j] * va[j].y + I0[j] * va[j].x;
            R0[j]    = nr;
            nr       = R1[j] * vb[j].x - I1[j] * vb[j].y;
            I1[j]    = R1[j] * vb[j].y + I1[j] * vb[j].x;
            R1[j]    = nr;
        }
        dft8<true>(R0, I0); dft8<true>(R1, I1);
        #pragma unroll
        for (int j = 0; j < 8; ++j) {
            *(float2*)(pa + S1 * j) = make_float2(R0[j], I0[j]);
            *(float2*)(pb + S1 * j) = make_float2(R1[j], I1[j]);
        }
    }
    __syncthreads();

    // pass 2 inv
    {
        const int P0 = 2 * e, P1 = 2 * e + 1;
        float* pa = lds + q * CST + (P0 >> 3) * S1 + (P0 & 7) * 2;
        float* pb = lds + q * CST + (P1 >> 3) * S1 + (P1 & 7) * 2;
        #pragma unroll
        for (int j = 0; j < 8; ++j) {
            const float2 za = *(const float2*)(pa + S2 * j);
            const float2 zb = *(const float2*)(pb + S2 * j);
            R0[j] = za.x; I0[j] = za.y; R1[j] = zb.x; I1[j] = zb.y;
        }
        dft8<true>(R0, I0); dft8<true>(R1, I1);
        #pragma unroll
        for (int j = 0; j < 8; ++j) {
            *(float2*)(pa + S2 * j) = make_float2(R0[j], I0[j]);
            *(float2*)(pb + S2 * j) = make_float2(R1[j], I1[j]);
        }
    }
    __syncthreads();

    // pass 3 inv (keep full complex: re=ch c, im=ch c+8 — both are outputs)
    {
        const int P0 = 2 * e, P1 = 2 * e + 1;
        float* pa = lds + q * CST + (P0 >> 3) * S1 + (P0 & 7) * S2;
        float* pb = lds + q * CST + (P1 >> 3) * S1 + (P1 & 7) * S2;
        #pragma unroll
        for (int j = 0; j < 8; ++j) {
            const float2 za = *(const float2*)(pa + 2 * j);
            const float2 zb = *(const float2*)(pb + 2 * j);
            R0[j] = za.x; I0[j] = za.y; R1[j] = zb.x; I1[j] = zb.y;
        }
        dft8<true>(R0, I0); dft8<true>(R1, I1);
        #pragma unroll
        for (int j = 0; j < 8; ++j) {
            *(float2*)(pa + 2 * j) = make_float2(R0[j], I0[j]);
            *(float2*)(pb + 2 * j) = make_float2(R1[j], I1[j]);
        }
    }
    __syncthreads();

    // copy-out (unpack: re -> channel c, im -> channel c+8)
    #pragma unroll
    for (int t = 0; t < 4; ++t) {
        const int G = t * 256 + tid;
        const int p = G >> 1;
        const int u = G & 1;
        const int base = (p >> 6) * S1 + ((p >> 3) & 7) * S2 + (p & 7) * 2;
        const float* src = lds + (u * 4) * CST + base;
        const float2 z0 = *(const float2*)(src + 0 * CST);
        const float2 z1 = *(const float2*)(src + 1 * CST);
        const float2 z2 = *(const float2*)(src + 2 * CST);
        const float2 z3 = *(const float2*)(src + 3 * CST);
        *(float4*)(ob + p * 512 + u * 4)     = make_float4(z0.x, z1.x, z2.x, z3.x);
        *(float4*)(ob + p * 512 + u * 4 + 8) = make_float4(z0.y, z1.y, z2.y, z3.y);
    }
}

extern "C" void kernel_launch(void* const* d_in, const int* in_sizes, int n_in,
                              void* d_out, int out_size, void* d_ws, size_t ws_size,
                              hipStream_t stream)
{
    const float* x      = (const float*)d_in[0];   // [32][512][512]
    const float* basis  = (const float*)d_in[1];   // [512][24]
    const float* kparam = (const float*)d_in[2];   // [24][8]
    float* out          = (float*)d_out;
    float2* V           = (float2*)d_ws;           // 8*512*8B = 32 KB scratch

    hipLaunchKernelGGL(eqfft_prep, dim3(128),  dim3(256), 0, stream, basis, kparam, V);
    hipLaunchKernelGGL(eqfft_main, dim3(1024), dim3(256), 0, stream, x, V, out);
}